// Round 4
// baseline (178.152 us; speedup 1.0000x reference)
//
#include <hip/hip_runtime.h>
#include <math.h>

typedef unsigned int uint;
typedef unsigned short ushort;

typedef __attribute__((ext_vector_type(8))) _Float16 f16x8;
typedef __attribute__((ext_vector_type(2))) _Float16 f16x2;
typedef __attribute__((ext_vector_type(16))) float floatx16;

#define NFEAT 327680   // 256*1280 feats (f16)
#define NW    491520   // 128*3840 W (f16)
// ws: fH f16[NFEAT] | wH f16[NW] | stats f32[16] | Aoi f32[128*256]

union U4H8 { uint4 u; f16x8 h; uint w[4]; };

__device__ inline ushort f2h(float f) {
  _Float16 h = (_Float16)f;          // v_cvt_f16_f32, RNE
  union { _Float16 h; ushort s; } c; c.h = h; return c.s;
}
__device__ inline f16x2 asf16x2(uint u) {
  union { uint u; f16x2 h; } c; c.u = u; return c.h;
}
__device__ inline uint asuint(f16x2 h) {
  union { f16x2 h; uint u; } c; c.h = h; return c.u;
}

// async global->LDS DMA, 16B/lane; lds dest wave-uniform base (+lane*16 implicit)
__device__ inline void async16(const ushort* g, ushort* l) {
  __builtin_amdgcn_global_load_lds((const __attribute__((address_space(1))) uint*)g,
                                   (__attribute__((address_space(3))) uint*)l, 16, 0, 0);
}

// ---------------- prep: fp32 -> fp16, zero stats + Aoi ----------------
__global__ void prep_kernel(const float* __restrict__ feats,
                            const float* __restrict__ W,
                            ushort* __restrict__ fH,
                            ushort* __restrict__ wH,
                            float* __restrict__ stats,
                            float* __restrict__ Aoi) {
  int idx = blockIdx.x * 256 + threadIdx.x;   // 3200*256 = NFEAT+NW
  if (blockIdx.x == 0 && threadIdx.x < 16) stats[threadIdx.x] = 0.0f;
  if (idx < 32768) Aoi[idx] = 0.0f;
  if (idx < NFEAT) fH[idx] = f2h(feats[idx]);
  else             wH[idx - NFEAT] = f2h(W[idx - NFEAT]);
}

// ---------------- A[o,i] = sum_c Wa[o,c]*f[i,c] ----------------
// grid 128: 8 i-tiles x 4 kq x 4 ot
__global__ __launch_bounds__(256, 2) void gemma_kernel(
    const ushort* __restrict__ fH, const ushort* __restrict__ wH,
    float* __restrict__ Aoi) {
  __shared__ float red[4][1024];
  const int tid = threadIdx.x, lane = tid & 63, w = tid >> 6;
  const int i0 = (blockIdx.x >> 4) << 5;
  const int kq = (blockIdx.x >> 2) & 3;
  const int ot = blockIdx.x & 3;
  const int rr = lane & 31, half = lane >> 5;
  floatx16 a4;
  #pragma unroll
  for (int r = 0; r < 16; ++r) a4[r] = 0.0f;
  const int kbase = kq * 320 + w * 80 + half * 8;
  #pragma unroll
  for (int ks = 0; ks < 5; ++ks) {
    const int k = kbase + ks * 16;
    U4H8 bf; bf.u = *(const uint4*)(fH + (i0 + rr) * 1280 + k);
    U4H8 af; af.u = *(const uint4*)(wH + (ot * 32 + rr) * 3840 + k);
    a4 = __builtin_amdgcn_mfma_f32_32x32x16_f16(af.h, bf.h, a4, 0, 0, 0);
  }
  #pragma unroll
  for (int r = 0; r < 16; ++r) {
    const int orow = (r & 3) + 8 * (r >> 2) + 4 * half;
    red[w][orow * 32 + rr] = a4[r];
  }
  __syncthreads();
  for (int e = tid; e < 1024; e += 256) {
    float s = red[0][e] + red[1][e] + red[2][e] + red[3][e];
    atomicAdd(&Aoi[(ot * 32 + (e >> 5)) * 256 + i0 + (e & 31)], s);
  }
}

// build diff/had B-fragments: packed f16, no unpack/repack.
// per packed pair: v_pk_add_f16(neg) + v_and_b32 + v_pk_mul_f16 = 3 VALU
__device__ inline void build_pair(const uint4 vj, const uint4 vi, U4H8& d, U4H8& h) {
  const uint ju[4] = {vj.x, vj.y, vj.z, vj.w};
  const uint iu[4] = {vi.x, vi.y, vi.z, vi.w};
  #pragma unroll
  for (int t = 0; t < 4; ++t) {
    f16x2 a = asf16x2(iu[t]);
    f16x2 b = asf16x2(ju[t]);
    f16x2 dd = a - b;
    f16x2 hh = a * b;
    d.w[t] = asuint(dd) & 0x7fff7fffu;   // |a-b| (clear both sign bits)
    h.w[t] = asuint(hh);
  }
}

// ---------------- main fused GEMM: diff+had, K=2560 ----------------
// R9: occupancy push. Grid 1024 = 128 i-pairs x 8 j-blocks(32j).
// Block = 2i x 128o x 32j, 4 waves; each wave owns a 32-o stripe (no ot
// loop, acc[2]). Same swizzled 32 KB LDS W-dbuf, vmcnt(4)+s_barrier.
// 4 blocks/CU (128 KB LDS, VGPR<=128 via launch_bounds(256,4)) ->
// 4 waves/SIMD; independent blocks' barrier stalls overlap.
__global__ __launch_bounds__(256, 4) void gemm_kernel(
    const ushort* __restrict__ fH, const ushort* __restrict__ wH,
    const float* __restrict__ bias, const float* __restrict__ Aoi,
    float* __restrict__ xout, float* __restrict__ stats) {
  // LDS: [buf][row(128)][slot(8)*8ush], slot = octet ^ (row&7); octet = term*4+st*2+half
  __shared__ __align__(16) ushort Wl[2 * 128 * 64];  // 32 KB

  const int tid = threadIdx.x;
  const int blk = blockIdx.x;          // 1024 = 128 i-pairs * 8 j-blocks
  const int i0 = (blk >> 3) << 1;      // first of 2 i-rows
  const int j0 = (blk & 7) << 5;
  const int lane = tid & 63;
  const int w = tid >> 6;
  const int wo = w << 5;               // wave's 32-o stripe
  const int rr = lane & 31;
  const int half = lane >> 5;
  const int rr7 = lane & 7;

  // DMA source: 4 per wave; DMA (w,p) fills rows [(w*4+p)*8, +8) x 8 slots
  const ushort* gsrc[4];
  #pragma unroll
  for (int p = 0; p < 4; ++p) {
    const int seg = w * 4 + p;
    const int row = seg * 8 + (lane >> 3);
    const int g = (lane & 7) ^ (lane >> 3);
    gsrc[p] = wH + row * 3840 + 1280 + (g >> 2) * 1280 + (g & 3) * 8;
  }

  const ushort* fi0p = fH + i0 * 1280 + half * 8;
  const ushort* fi1p = fi0p + 1280;
  const ushort* fjp = fH + (j0 + rr) * 1280 + half * 8;

  floatx16 acc[2];   // [i]
  #pragma unroll
  for (int a = 0; a < 2; ++a)
    #pragma unroll
    for (int r = 0; r < 16; ++r) acc[a][r] = 0.0f;

  // prologue: DMA chunk 0 into buf 0, prefetch fi/fj chunk 0
  #pragma unroll
  for (int p = 0; p < 4; ++p)
    async16(gsrc[p], &Wl[(w * 4 + p) * 512]);
  uint4 vi0[2], vi1[2], vj[2];
  #pragma unroll
  for (int st = 0; st < 2; ++st) {
    vj[st]  = *(const uint4*)(fjp  + st * 16);
    vi0[st] = *(const uint4*)(fi0p + st * 16);
    vi1[st] = *(const uint4*)(fi1p + st * 16);
  }
  __syncthreads();   // one full drain at prologue is fine

  for (int cc = 0; cc < 40; ++cc) {
    const ushort* Wc = &Wl[(cc & 1) * 8192];
    uint4 vi0n[2], vi1n[2], vjn[2];
    if (cc < 39) {
      const int cn = (cc + 1) << 5;
      #pragma unroll
      for (int p = 0; p < 4; ++p)
        async16(gsrc[p] + cn, &Wl[((cc & 1) ^ 1) * 8192 + (w * 4 + p) * 512]);
      __builtin_amdgcn_sched_barrier(0);   // pin: DMAs issue first
      #pragma unroll
      for (int st = 0; st < 2; ++st) {
        vjn[st]  = *(const uint4*)(fjp  + cn + st * 16);
        vi0n[st] = *(const uint4*)(fi0p + cn + st * 16);
        vi1n[st] = *(const uint4*)(fi1p + cn + st * 16);
      }
      __builtin_amdgcn_sched_barrier(0);   // pin: loads after DMAs, before compute
    }
    #pragma unroll
    for (int st = 0; st < 2; ++st) {
      U4H8 d0, h0, d1, h1;
      build_pair(vj[st], vi0[st], d0, h0);
      build_pair(vj[st], vi1[st], d1, h1);
      const int g0 = (st << 1) + half;        // term-0 octet (0..3)
      const int rowb = (wo + rr) << 6;
      f16x8 ad = *(const f16x8*)(Wc + rowb + ((g0 ^ rr7) << 3));
      f16x8 ah = *(const f16x8*)(Wc + rowb + (((g0 + 4) ^ rr7) << 3));
      acc[0] = __builtin_amdgcn_mfma_f32_32x32x16_f16(ad, d0.h, acc[0], 0, 0, 0);
      acc[1] = __builtin_amdgcn_mfma_f32_32x32x16_f16(ad, d1.h, acc[1], 0, 0, 0);
      acc[0] = __builtin_amdgcn_mfma_f32_32x32x16_f16(ah, h0.h, acc[0], 0, 0, 0);
      acc[1] = __builtin_amdgcn_mfma_f32_32x32x16_f16(ah, h1.h, acc[1], 0, 0, 0);
    }
    if (cc < 39) {
      __builtin_amdgcn_sched_barrier(0);       // keep compute (ds_reads) above
      __builtin_amdgcn_s_waitcnt(0x0F74);      // vmcnt(4): retire the 4 DMAs
      __builtin_amdgcn_s_barrier();
      __builtin_amdgcn_sched_barrier(0);       // nothing hoists above barrier
      __asm__ volatile("" ::: "memory");       // no LDS value caching across it
      #pragma unroll
      for (int st = 0; st < 2; ++st) {
        vj[st] = vjn[st]; vi0[st] = vi0n[st]; vi1[st] = vi1n[st];
      }
    }
  }

  // epilogue: add A[o,i]+A[o,j]+b[o], store, group stats (both i-rows)
  float gs[2] = {0.f, 0.f};
  float gq[2] = {0.f, 0.f};
  const int jg = j0 + rr;
  #pragma unroll
  for (int ii = 0; ii < 2; ++ii) {
    const int irow = i0 + ii;
    const int mglob = irow * 256 + jg;
    #pragma unroll
    for (int r = 0; r < 16; ++r) {
      const int orow = (r & 3) + 8 * (r >> 2) + 4 * half;  // D row map (m74/m101)
      const int o = wo + orow;
      float x = acc[ii][r] + Aoi[o * 256 + irow] + Aoi[o * 256 + jg] + bias[o];
      xout[o * 65536 + mglob] = x;
      gs[r >> 3] += x;
      gq[r >> 3] += x * x;
    }
  }
  __syncthreads();   // full drain before LDS reuse
  float* sred = (float*)Wl;
  if (tid < 16) sred[tid] = 0.0f;
  __syncthreads();
  #pragma unroll
  for (int rg = 0; rg < 2; ++rg) {
    float s = gs[rg], qv = gq[rg];
    for (int off = 32; off > 0; off >>= 1) {
      s += __shfl_xor(s, off, 64);
      qv += __shfl_xor(qv, off, 64);
    }
    if (lane == 0) {
      const int g = (w << 1) + rg;          // wave's 32-o stripe = groups 2w,2w+1
      atomicAdd(&sred[g], s);
      atomicAdd(&sred[8 + g], qv);
    }
  }
  __syncthreads();
  if (tid < 16) atomicAdd(&stats[tid], sred[tid]);
}

// ---------------- groupnorm + exact gelu, in place ----------------
__global__ void norm_kernel(float* __restrict__ xout,
                            const float* __restrict__ stats,
                            const float* __restrict__ gamma,
                            const float* __restrict__ beta) {
  const int idx = blockIdx.x * 256 + threadIdx.x;
  const int e = idx << 2;
  const int o = e >> 16;
  const int g = o >> 4;
  const float invN = 1.0f / 1048576.0f;  // 16*65536 per group
  const float mean = stats[g] * invN;
  const float var = stats[8 + g] * invN - mean * mean;
  const float inv = rsqrtf(var + 1e-5f);
  const float ga = gamma[o], be = beta[o];
  float4 v = *(float4*)(xout + e);
  float* pv = &v.x;
  #pragma unroll
  for (int t = 0; t < 4; ++t) {
    float xn = (pv[t] - mean) * inv * ga + be;
    pv[t] = 0.5f * xn * (1.0f + erff(xn * 0.70710678118654752f));
  }
  *(float4*)(xout + e) = v;
}

extern "C" void kernel_launch(void* const* d_in, const int* in_sizes, int n_in,
                              void* d_out, int out_size, void* d_ws, size_t ws_size,
                              hipStream_t stream) {
  const float* feats = (const float*)d_in[0];
  const float* W     = (const float*)d_in[1];
  const float* bias  = (const float*)d_in[2];
  const float* gamma = (const float*)d_in[3];
  const float* beta  = (const float*)d_in[4];
  float* out = (float*)d_out;

  ushort* fH = (ushort*)d_ws;
  ushort* wH = fH + NFEAT;
  float* stats = (float*)(wH + NW);
  float* Aoi = stats + 16;

  prep_kernel<<<3200, 256, 0, stream>>>(feats, W, fH, wH, stats, Aoi);
  gemma_kernel<<<128, 256, 0, stream>>>(fH, wH, Aoi);
  gemm_kernel<<<1024, 256, 0, stream>>>(fH, wH, bias, Aoi, out, stats);
  norm_kernel<<<8192, 256, 0, stream>>>(out, stats, gamma, beta);
}

// Round 5
// 144.390 us; speedup vs baseline: 1.2338x; 1.2338x over previous
//
#include <hip/hip_runtime.h>
#include <math.h>

typedef unsigned int uint;
typedef unsigned short ushort;

typedef __attribute__((ext_vector_type(8))) _Float16 f16x8;
typedef __attribute__((ext_vector_type(2))) _Float16 f16x2;
typedef __attribute__((ext_vector_type(16))) float floatx16;

#define NFEAT 327680   // 256*1280 feats (f16)
#define NWA   163840   // W add-part, row-major [128][1280] (f16)
#define NWP   327680   // W diff/had part, fragment-packed (f16)
// ws: fH | wA | wP | stats f32[16] | Aoi f32[128*256]

union U4H8 { uint4 u; f16x8 h; uint w[4]; };

__device__ inline ushort f2h(float f) {
  _Float16 h = (_Float16)f;          // v_cvt_f16_f32, RNE
  union { _Float16 h; ushort s; } c; c.h = h; return c.s;
}
__device__ inline f16x2 asf16x2(uint u) {
  union { uint u; f16x2 h; } c; c.u = u; return c.h;
}
__device__ inline uint asuint(f16x2 h) {
  union { f16x2 h; uint u; } c; c.h = h; return c.u;
}

// ---------------- prep: fp32 -> fp16; W diff/had part packed into MFMA
// A-fragment order. Tile (ks 0..79, t 0..1, ob 0..3) = 512 ushorts:
// lane(0..63) = khalf*32 + (o&31) holds W[o][1280 + t*1280 + ks*16 + khalf*8 + 0..7].
__global__ void prep_kernel(const float* __restrict__ feats,
                            const float* __restrict__ W,
                            ushort* __restrict__ fH,
                            ushort* __restrict__ wA,
                            ushort* __restrict__ wP,
                            float* __restrict__ stats,
                            float* __restrict__ Aoi) {
  int idx = blockIdx.x * 256 + threadIdx.x;   // 3200*256 = NFEAT+NWA+NWP
  if (blockIdx.x == 0 && threadIdx.x < 16) stats[threadIdx.x] = 0.0f;
  if (idx < 32768) Aoi[idx] = 0.0f;
  if (idx < NFEAT) {
    fH[idx] = f2h(feats[idx]);
  } else {
    const int e = idx - NFEAT;
    const int o = e / 3840;
    const int c = e - o * 3840;
    const ushort v = f2h(W[e]);
    if (c < 1280) {
      wA[o * 1280 + c] = v;
    } else {
      const int cp = c - 1280;
      const int t = cp / 1280;            // 0=diff, 1=had
      const int kk = cp - t * 1280;
      const int ks = kk >> 4;
      const int khalf = (kk >> 3) & 1;
      const int ko = kk & 7;
      const int lane = khalf * 32 + (o & 31);
      const int tile = (ks * 2 + t) * 4 + (o >> 5);
      wP[tile * 512 + lane * 8 + ko] = v;
    }
  }
}

// ---------------- A[o,i] = sum_c Wa[o,c]*f[i,c] ----------------
// grid 128: 8 i-tiles x 4 kq x 4 ot
__global__ __launch_bounds__(256, 2) void gemma_kernel(
    const ushort* __restrict__ fH, const ushort* __restrict__ wA,
    float* __restrict__ Aoi) {
  __shared__ float red[4][1024];
  const int tid = threadIdx.x, lane = tid & 63, w = tid >> 6;
  const int i0 = (blockIdx.x >> 4) << 5;
  const int kq = (blockIdx.x >> 2) & 3;
  const int ot = blockIdx.x & 3;
  const int rr = lane & 31, half = lane >> 5;
  floatx16 a4;
  #pragma unroll
  for (int r = 0; r < 16; ++r) a4[r] = 0.0f;
  const int kbase = kq * 320 + w * 80 + half * 8;
  #pragma unroll
  for (int ks = 0; ks < 5; ++ks) {
    const int k = kbase + ks * 16;
    U4H8 bf; bf.u = *(const uint4*)(fH + (i0 + rr) * 1280 + k);
    U4H8 af; af.u = *(const uint4*)(wA + (ot * 32 + rr) * 1280 + k);
    a4 = __builtin_amdgcn_mfma_f32_32x32x16_f16(af.h, bf.h, a4, 0, 0, 0);
  }
  #pragma unroll
  for (int r = 0; r < 16; ++r) {
    const int orow = (r & 3) + 8 * (r >> 2) + 4 * half;
    red[w][orow * 32 + rr] = a4[r];
  }
  __syncthreads();
  for (int e = tid; e < 1024; e += 256) {
    float s = red[0][e] + red[1][e] + red[2][e] + red[3][e];
    atomicAdd(&Aoi[(ot * 32 + (e >> 5)) * 256 + i0 + (e & 31)], s);
  }
}

// build diff/had B-fragments: packed f16, no unpack/repack.
__device__ inline void build_pair(const uint4 vj, const uint4 vi, U4H8& d, U4H8& h) {
  const uint ju[4] = {vj.x, vj.y, vj.z, vj.w};
  const uint iu[4] = {vi.x, vi.y, vi.z, vi.w};
  #pragma unroll
  for (int t = 0; t < 4; ++t) {
    f16x2 a = asf16x2(iu[t]);
    f16x2 b = asf16x2(ju[t]);
    f16x2 dd = a - b;
    f16x2 hh = a * b;
    d.w[t] = asuint(dd) & 0x7fff7fffu;   // |a-b| (clear both sign bits)
    h.w[t] = asuint(hh);
  }
}

// ---------------- main fused GEMM: diff+had, K=2560 ----------------
// R10: no LDS, no barriers, no DMA in the K-loop. W comes fragment-packed
// from global (L2-resident, coalesced 16B/lane), double-register-buffered
// (A/B sets, static indexing). Grid 512 = 128 i-pairs x 4 j-blocks; block
// = 2i x 128o x 64j, 4 waves (2 o-stripes x 2 j-stripes); wave = 2i x 64o
// x 32j = 16 MFMA/chunk over 4 independent acc chains.
__global__ __launch_bounds__(256, 2) void gemm_kernel(
    const ushort* __restrict__ fH, const ushort* __restrict__ wP,
    const float* __restrict__ bias, const float* __restrict__ Aoi,
    float* __restrict__ xout, float* __restrict__ stats) {
  __shared__ float sred[16];

  const int tid = threadIdx.x;
  const int blk = blockIdx.x;          // 512 = 128 i-pairs * 4 j-blocks
  const int i0 = (blk >> 2) << 1;      // first of 2 i-rows
  const int j0 = (blk & 3) << 6;
  const int lane = tid & 63;
  const int w = tid >> 6;
  const int wo = (w >> 1) << 6;
  const int wm = (w & 1) << 5;
  const int rr = lane & 31;
  const int half = lane >> 5;

  // per-lane W-fragment base: ob0*512 + lane*8 (ushort units)
  const ushort* wpl = wP + ((wo >> 5) << 9) + lane * 8;
  const ushort* fi0p = fH + i0 * 1280 + half * 8;
  const ushort* fi1p = fi0p + 1280;
  const ushort* fjp  = fH + (j0 + wm + rr) * 1280 + half * 8;

  floatx16 acc[2][2];   // [i][ot]
  #pragma unroll
  for (int a = 0; a < 2; ++a)
    #pragma unroll
    for (int ot = 0; ot < 2; ++ot)
      #pragma unroll
      for (int r = 0; r < 16; ++r) acc[a][ot][r] = 0.0f;

  U4H8 wfA[8], wfB[8];
  uint4 vjA[2], viA0[2], viA1[2], vjB[2], viB0[2], viB1[2];

  // frag index q = st*4 + t*2 + oi; tile = cc*16 + st*8 + t*4 + oi
#define CHUNK_LOAD(WF, VJ, VI0, VI1, CC) do {                                 \
    const int _b = (CC) * 16;                                                 \
    _Pragma("unroll")                                                         \
    for (int _q = 0; _q < 8; ++_q) {                                          \
      const int _st = _q >> 2, _t = (_q >> 1) & 1, _oi = _q & 1;              \
      (WF)[_q].u = *(const uint4*)(wpl + ((_b + _st * 8 + _t * 4 + _oi) << 9)); \
    }                                                                         \
    const int _cb = (CC) << 5;                                                \
    _Pragma("unroll")                                                         \
    for (int _s = 0; _s < 2; ++_s) {                                          \
      (VJ)[_s]  = *(const uint4*)(fjp  + _cb + _s * 16);                      \
      (VI0)[_s] = *(const uint4*)(fi0p + _cb + _s * 16);                      \
      (VI1)[_s] = *(const uint4*)(fi1p + _cb + _s * 16);                      \
    }                                                                         \
  } while (0)

#define CHUNK_COMPUTE(WF, VJ, VI0, VI1) do {                                  \
    _Pragma("unroll")                                                         \
    for (int _s = 0; _s < 2; ++_s) {                                          \
      U4H8 d0, h0, d1, h1;                                                    \
      build_pair((VJ)[_s], (VI0)[_s], d0, h0);                                \
      build_pair((VJ)[_s], (VI1)[_s], d1, h1);                                \
      acc[0][0] = __builtin_amdgcn_mfma_f32_32x32x16_f16((WF)[_s*4+0].h, d0.h, acc[0][0], 0, 0, 0); \
      acc[1][0] = __builtin_amdgcn_mfma_f32_32x32x16_f16((WF)[_s*4+0].h, d1.h, acc[1][0], 0, 0, 0); \
      acc[0][1] = __builtin_amdgcn_mfma_f32_32x32x16_f16((WF)[_s*4+1].h, d0.h, acc[0][1], 0, 0, 0); \
      acc[1][1] = __builtin_amdgcn_mfma_f32_32x32x16_f16((WF)[_s*4+1].h, d1.h, acc[1][1], 0, 0, 0); \
      acc[0][0] = __builtin_amdgcn_mfma_f32_32x32x16_f16((WF)[_s*4+2].h, h0.h, acc[0][0], 0, 0, 0); \
      acc[1][0] = __builtin_amdgcn_mfma_f32_32x32x16_f16((WF)[_s*4+2].h, h1.h, acc[1][0], 0, 0, 0); \
      acc[0][1] = __builtin_amdgcn_mfma_f32_32x32x16_f16((WF)[_s*4+3].h, h0.h, acc[0][1], 0, 0, 0); \
      acc[1][1] = __builtin_amdgcn_mfma_f32_32x32x16_f16((WF)[_s*4+3].h, h1.h, acc[1][1], 0, 0, 0); \
    }                                                                         \
  } while (0)

  CHUNK_LOAD(wfA, vjA, viA0, viA1, 0);
  #pragma unroll 1
  for (int cc = 0; cc < 40; cc += 2) {
    CHUNK_LOAD(wfB, vjB, viB0, viB1, cc + 1);     // prefetch odd chunk
    CHUNK_COMPUTE(wfA, vjA, viA0, viA1);          // compute even chunk
    if (cc + 2 < 40)
      CHUNK_LOAD(wfA, vjA, viA0, viA1, cc + 2);   // prefetch next even
    CHUNK_COMPUTE(wfB, vjB, viB0, viB1);          // compute odd chunk
  }
#undef CHUNK_LOAD
#undef CHUNK_COMPUTE

  // epilogue: add A[o,i]+A[o,j]+b[o], store, group stats (both i-rows)
  float gs[2][2] = {{0.f, 0.f}, {0.f, 0.f}};
  float gq[2][2] = {{0.f, 0.f}, {0.f, 0.f}};
  const int jg = j0 + wm + rr;
  #pragma unroll
  for (int ii = 0; ii < 2; ++ii) {
    const int irow = i0 + ii;
    const int mglob = irow * 256 + jg;
    #pragma unroll
    for (int ot = 0; ot < 2; ++ot) {
      #pragma unroll
      for (int r = 0; r < 16; ++r) {
        const int orow = (r & 3) + 8 * (r >> 2) + 4 * half;  // D row map (m74/m101)
        const int o = wo + ot * 32 + orow;
        float x = acc[ii][ot][r] + Aoi[o * 256 + irow] + Aoi[o * 256 + jg] + bias[o];
        xout[o * 65536 + mglob] = x;
        gs[ot][r >> 3] += x;
        gq[ot][r >> 3] += x * x;
      }
    }
  }
  if (tid < 16) sred[tid] = 0.0f;
  __syncthreads();
  #pragma unroll
  for (int ot = 0; ot < 2; ++ot) {
    #pragma unroll
    for (int rg = 0; rg < 2; ++rg) {
      float s = gs[ot][rg], qv = gq[ot][rg];
      for (int off = 32; off > 0; off >>= 1) {
        s += __shfl_xor(s, off, 64);
        qv += __shfl_xor(qv, off, 64);
      }
      if (lane == 0) {
        const int g = (wo >> 4) + ot * 2 + rg;
        atomicAdd(&sred[g], s);
        atomicAdd(&sred[8 + g], qv);
      }
    }
  }
  __syncthreads();
  if (tid < 16) atomicAdd(&stats[tid], sred[tid]);
}

// ---------------- groupnorm + exact gelu, in place ----------------
__global__ void norm_kernel(float* __restrict__ xout,
                            const float* __restrict__ stats,
                            const float* __restrict__ gamma,
                            const float* __restrict__ beta) {
  const int idx = blockIdx.x * 256 + threadIdx.x;
  const int e = idx << 2;
  const int o = e >> 16;
  const int g = o >> 4;
  const float invN = 1.0f / 1048576.0f;  // 16*65536 per group
  const float mean = stats[g] * invN;
  const float var = stats[8 + g] * invN - mean * mean;
  const float inv = rsqrtf(var + 1e-5f);
  const float ga = gamma[o], be = beta[o];
  float4 v = *(float4*)(xout + e);
  float* pv = &v.x;
  #pragma unroll
  for (int t = 0; t < 4; ++t) {
    float xn = (pv[t] - mean) * inv * ga + be;
    pv[t] = 0.5f * xn * (1.0f + erff(xn * 0.70710678118654752f));
  }
  *(float4*)(xout + e) = v;
}

extern "C" void kernel_launch(void* const* d_in, const int* in_sizes, int n_in,
                              void* d_out, int out_size, void* d_ws, size_t ws_size,
                              hipStream_t stream) {
  const float* feats = (const float*)d_in[0];
  const float* W     = (const float*)d_in[1];
  const float* bias  = (const float*)d_in[2];
  const float* gamma = (const float*)d_in[3];
  const float* beta  = (const float*)d_in[4];
  float* out = (float*)d_out;

  ushort* fH = (ushort*)d_ws;
  ushort* wA = fH + NFEAT;
  ushort* wP = wA + NWA;
  float* stats = (float*)(wP + NWP);
  float* Aoi = stats + 16;

  prep_kernel<<<3200, 256, 0, stream>>>(feats, W, fH, wA, wP, stats, Aoi);
  gemma_kernel<<<128, 256, 0, stream>>>(fH, wA, Aoi);
  gemm_kernel<<<512, 256, 0, stream>>>(fH, wP, bias, Aoi, out, stats);
  norm_kernel<<<8192, 256, 0, stream>>>(out, stats, gamma, beta);
}